// Round 4
// baseline (141.483 us; speedup 1.0000x reference)
//
#include <hip/hip_runtime.h>
#include <hip/hip_bf16.h>

#define EDIM 256
#define NROWS 8192
#define GRIDX 4
#define GRIDY 64
#define NBLOCKS (GRIDX * GRIDY)

typedef __attribute__((ext_vector_type(8))) short bf16x8;
typedef __attribute__((ext_vector_type(4))) float f32x4;

__device__ __forceinline__ unsigned short f2bf(float f) {
  unsigned int u = __float_as_uint(f);
  unsigned int r = (u + 0x7fffu + ((u >> 16) & 1u)) >> 16;  // RNE
  return (unsigned short)r;
}

// ---------------------------------------------------------------------------
// Kernel 1: normalize + transpose -> bf16 W[8192][256]; zero S and done.
// ---------------------------------------------------------------------------
__global__ __launch_bounds__(256) void detcon_normalize(
    const float* __restrict__ v0, const float* __restrict__ v1,
    __hip_bfloat16* __restrict__ Wb, float* __restrict__ S,
    unsigned int* __restrict__ done) {
  __shared__ float Xs[EDIM][32];
  __shared__ float part[4][32];
  __shared__ float scale_s[32];
  const int t = threadIdx.x;
  const int bid = blockIdx.x;              // 0..255
  if (t < 32) S[bid * 32 + t] = 0.0f;      // zero S (8192 = 256*32)
  if (bid == 0 && t == 0) *done = 0u;
  const int view = bid >> 7;
  const int b = (bid >> 1) & 63;
  const int nh = (bid & 1) * 32;
  const float* src = (view ? v1 : v0) + (size_t)b * (EDIM * 64);

  const int n4 = t & 7;
  const int eg = t >> 3;
  float4 ss = {0.f, 0.f, 0.f, 0.f};
#pragma unroll
  for (int i = 0; i < 8; ++i) {
    const int e = i * 32 + eg;
    float4 x = *(const float4*)(src + e * 64 + nh + n4 * 4);
    *(float4*)(&Xs[e][n4 * 4]) = x;
    ss.x += x.x * x.x; ss.y += x.y * x.y; ss.z += x.z * x.z; ss.w += x.w * x.w;
  }
#pragma unroll
  for (int m = 8; m <= 32; m <<= 1) {
    ss.x += __shfl_xor(ss.x, m, 64);
    ss.y += __shfl_xor(ss.y, m, 64);
    ss.z += __shfl_xor(ss.z, m, 64);
    ss.w += __shfl_xor(ss.w, m, 64);
  }
  if ((t & 63) < 8) *(float4*)(&part[t >> 6][(t & 7) * 4]) = ss;
  __syncthreads();
  if (t < 32) {
    const float total = part[0][t] + part[1][t] + part[2][t] + part[3][t];
    scale_s[t] = 3.16227766016838f / (sqrtf(total) + 1e-8f);
  }
  __syncthreads();

  const int nl = t >> 3;
  const int e0 = (t & 7) * 32;
  const float sc = scale_s[nl];
  const size_t r = (size_t)view * 4096 + (size_t)b * 64 + nh + nl;
  __hip_bfloat16* dst = Wb + r * EDIM;
#pragma unroll
  for (int j = 0; j < 4; ++j) {
    bf16x8 o;
#pragma unroll
    for (int u = 0; u < 8; ++u)
      o[u] = (short)f2bf(Xs[e0 + j * 8 + u][nl] * sc);
    *(bf16x8*)(dst + e0 + j * 8) = o;
  }
}

// ---------------------------------------------------------------------------
// Kernel 2: fused Gram + sum-of-exp, NO LDS / NO barriers in the loop.
// Grid (4,64)=256 blocks, 512 thr = 8 waves (2 wrow x 4 wcol).
// Wave = 64 rows (A full-K in regs) x 16-col strip per iter, 32 iters.
// B-fragments loaded DIRECTLY from global W (row-major): each bf16x8 load
// touches 16 fully-utilized 64B lines, L2-resident; compiler pipelines loads
// under MFMAs freely (no barrier ever drains vmcnt).
// Diag/pos logits extracted in-loop; last block (done-counter) finalizes.
// ---------------------------------------------------------------------------
__global__ __launch_bounds__(512, 2) void detcon_gram(
    const __hip_bfloat16* __restrict__ Wbh, float* __restrict__ S,
    float* __restrict__ sd, float* __restrict__ pd,
    unsigned int* __restrict__ done, float* __restrict__ out) {
  __shared__ float red[8];
  __shared__ int lastFlag;
  const int tid = threadIdx.x;
  const int lane = tid & 63;
  const int wid = tid >> 6;                 // 0..7
  const int wrow = wid >> 2;                // 0..1
  const int wcol = wid & 3;                 // 0..3
  const int rowbase = blockIdx.y * 128 + wrow * 64;
  const int colblock = blockIdx.x * 2048;
  const unsigned short* W = (const unsigned short*)Wbh;

  // A fragments, full K: lane holds A[rowbase+m*16+(lane&15)][kb*32+(lane>>4)*8 ..+8]
  bf16x8 a[4][8];
#pragma unroll
  for (int m = 0; m < 4; ++m) {
    const unsigned row = rowbase + m * 16 + (lane & 15);
#pragma unroll
    for (int kb = 0; kb < 8; ++kb)
      a[m][kb] = *(const bf16x8*)(W + (row << 8) + kb * 32 + (lane >> 4) * 8);
  }

  f32x4 acc[4];
  float s[4][4];
#pragma unroll
  for (int m = 0; m < 4; ++m) {
    acc[m] = (f32x4){0.f, 0.f, 0.f, 0.f};
#pragma unroll
    for (int j = 0; j < 4; ++j) s[m][j] = 0.f;
  }

  const int clo = lane & 15;
  const int koff = (lane >> 4) * 8;
  const int jl = clo - ((lane >> 4) << 2);

  for (int it = 0; it < 32; ++it) {
    const int strip0 = colblock + it * 64 + wcol * 16;
    const unsigned short* Bp = W + ((unsigned)(strip0 + clo) << 8) + koff;
    bf16x8 bf[8];
#pragma unroll
    for (int kb = 0; kb < 8; ++kb) bf[kb] = *(const bf16x8*)(Bp + kb * 32);
#pragma unroll
    for (int kb = 0; kb < 8; ++kb) {
#pragma unroll
      for (int m = 0; m < 4; ++m)
        acc[m] = __builtin_amdgcn_mfma_f32_16x16x32_bf16(a[m][kb], bf[kb],
                                                         acc[m], 0, 0, 0);
    }

    // ---- rare wave-uniform extraction of diag / positive logits ----
    const unsigned d0 = (unsigned)(strip0 - rowbase);
    if (d0 < 64u) {
      const int dm = (int)(d0 >> 4);
#pragma unroll
      for (int m = 0; m < 4; ++m)
        if (m == dm) {
#pragma unroll
          for (int j = 0; j < 4; ++j)
            if (j == jl) sd[strip0 + clo] = acc[m][j];
        }
    }
    const unsigned p0 = (unsigned)(((strip0 + 4096) & 8191) - rowbase);
    if (p0 < 64u) {
      const int pm = (int)(p0 >> 4);
#pragma unroll
      for (int m = 0; m < 4; ++m)
        if (m == pm) {
#pragma unroll
          for (int j = 0; j < 4; ++j)
            if (j == jl) pd[(strip0 + clo + 4096) & 8191] = acc[m][j];
        }
    }

    // ---- exp-accumulate (diag included; removed in finalize) ----
#pragma unroll
    for (int m = 0; m < 4; ++m) {
#pragma unroll
      for (int j = 0; j < 4; ++j) s[m][j] += __expf(acc[m][j]);
      acc[m] = (f32x4){0.f, 0.f, 0.f, 0.f};
    }
  }

  // ---- per-row sums: 16-lane shuffle reduce, atomicAdd into S ----
#pragma unroll
  for (int m = 0; m < 4; ++m) {
#pragma unroll
    for (int j = 0; j < 4; ++j) {
      float v = s[m][j];
      v += __shfl_xor(v, 1, 64);
      v += __shfl_xor(v, 2, 64);
      v += __shfl_xor(v, 4, 64);
      v += __shfl_xor(v, 8, 64);
      if ((lane & 15) == 0)
        atomicAdd(&S[rowbase + m * 16 + (lane >> 4) * 4 + j], v);
    }
  }

  // ---- grid completion: last block finalizes ----
  __syncthreads();  // every thread's S atomics / sd / pd stores drained
  if (tid == 0) {
    __threadfence();
    lastFlag = (atomicAdd(done, 1u) == (unsigned)(NBLOCKS - 1));
  }
  __syncthreads();
  if (lastFlag) {
    __threadfence();
    float local = 0.f;
    for (int r = tid; r < NROWS; r += 512)
      local += logf(S[r] - __expf(sd[r])) - pd[r];
#pragma unroll
    for (int m = 32; m >= 1; m >>= 1) local += __shfl_xor(local, m, 64);
    if ((tid & 63) == 0) red[tid >> 6] = local;
    __syncthreads();
    if (tid == 0) {
      float t = 0.f;
#pragma unroll
      for (int w = 0; w < 8; ++w) t += red[w];
      out[0] = t * (1.0f / (float)NROWS);
    }
  }
}

extern "C" void kernel_launch(void* const* d_in, const int* in_sizes, int n_in,
                              void* d_out, int out_size, void* d_ws, size_t ws_size,
                              hipStream_t stream) {
  const float* v0 = (const float*)d_in[0];
  const float* v1 = (const float*)d_in[1];
  float* out = (float*)d_out;

  // ws: Wb bf16[8192][256] | S f32[8192] | sd f32[8192] | pd f32[8192] | done u32
  __hip_bfloat16* Wb = (__hip_bfloat16*)d_ws;
  char* base = (char*)d_ws + (size_t)NROWS * EDIM * 2;
  float* S = (float*)base;
  float* sd = S + NROWS;
  float* pd = sd + NROWS;
  unsigned int* done = (unsigned int*)(pd + NROWS);

  detcon_normalize<<<256, 256, 0, stream>>>(v0, v1, Wb, S, done);
  detcon_gram<<<dim3(GRIDX, GRIDY), 512, 0, stream>>>(Wb, S, sd, pd, done, out);
}